// Round 12
// baseline (329.679 us; speedup 1.0000x reference)
//
#include <hip/hip_runtime.h>
#include <hip/hip_fp16.h>

#define NN 100000   // nodes
#define NE 1600000  // edges
#define NG 512      // graphs
#define NBLK 391    // ceil(NN/256) = coarse buckets (dst>>8), 256 nodes each
#define EPB 4096    // edges per csort batch block (32 KB LDS -> full CU coverage)
#define NCB 391     // ceil(NE/EPB)
#define HEPB 2048   // edges per bhist block
#define NHB 782     // ceil(NE/HEPB)
// IN=128, HID=128, OUT=64

typedef _Float16 half8 __attribute__((ext_vector_type(8)));
typedef _Float16 half4v __attribute__((ext_vector_type(4)));
typedef float floatx4 __attribute__((ext_vector_type(4)));

// ---------- bucket histogram: LDS-privatized, 391 global atomics per block ----------
__global__ __launch_bounds__(256) void k_bhist(const int* __restrict__ dst,
                                               int* __restrict__ bcnt) {
    __shared__ int h[NBLK];
    int t = threadIdx.x;
    for (int i = t; i < NBLK; i += 256) h[i] = 0;
    __syncthreads();
    int e0 = blockIdx.x * HEPB;
    int e1 = e0 + HEPB; if (e1 > NE) e1 = NE;
    for (int i = e0 + t; i < e1; i += 256) atomicAdd(&h[dst[i] >> 8], 1);
    __syncthreads();
    for (int i = t; i < NBLK; i += 256)
        if (h[i]) atomicAdd(&bcnt[i], h[i]);
}

// ---------- scan bucket counts -> bucket bases + csort cursors ----------
__global__ __launch_bounds__(512) void k_bscan(const int* __restrict__ bcnt,
                                               int* __restrict__ bbase,
                                               int* __restrict__ gcur) {
    __shared__ int s[512];
    int t = threadIdx.x;
    int v = (t < NBLK) ? bcnt[t] : 0;
    s[t] = v;
    __syncthreads();
    for (int d = 1; d < 512; d <<= 1) {
        int u = (t >= d) ? s[t - d] : 0;
        __syncthreads();
        s[t] += u;
        __syncthreads();
    }
    if (t < NBLK) {
        int ex = s[t] - v;
        bbase[t] = ex;
        gcur[t] = ex;
    }
    if (t == 0) bbase[NBLK] = NE;
}

// ---------- batch counting-sort edges into coarse-bucket regions ----------
__global__ __launch_bounds__(256) void k_csort(const int* __restrict__ src,
                                               const int* __restrict__ dst,
                                               int* __restrict__ gcur,
                                               unsigned* __restrict__ pairbuf) {
    __shared__ int hcnt[NBLK];
    __shared__ int lbase[NBLK];
    __shared__ int lcur[NBLK];
    __shared__ int gbase[NBLK];
    __shared__ int ss[512];
    __shared__ unsigned sorted[EPB];
    __shared__ unsigned short bkt[EPB];
    int t = threadIdx.x;
    int e0 = blockIdx.x * EPB;
    int e1 = e0 + EPB; if (e1 > NE) e1 = NE;
    int n = e1 - e0;

    for (int i = t; i < NBLK; i += 256) hcnt[i] = 0;
    __syncthreads();
    for (int i = e0 + t; i < e1; i += 256)
        atomicAdd(&hcnt[dst[i] >> 8], 1);
    __syncthreads();
    ss[t]       = (t < NBLK) ? hcnt[t] : 0;
    ss[t + 256] = (t + 256 < NBLK) ? hcnt[t + 256] : 0;
    __syncthreads();
    for (int d = 1; d < 512; d <<= 1) {
        int v1 = (t >= d) ? ss[t - d] : 0;
        int v2 = ss[t + 256 - d];
        __syncthreads();
        ss[t] += v1; ss[t + 256] += v2;
        __syncthreads();
    }
    for (int i = t; i < NBLK; i += 256) {
        int ex = ss[i] - hcnt[i];
        lbase[i] = ex;
        lcur[i] = ex;
        if (hcnt[i] > 0) gbase[i] = atomicAdd(&gcur[i], hcnt[i]);
    }
    __syncthreads();
    for (int i = e0 + t; i < e1; i += 256) {
        int d = dst[i];
        int b = d >> 8;
        int pos = atomicAdd(&lcur[b], 1);
        sorted[pos] = ((unsigned)(d & 255) << 24) | (unsigned)src[i];
        bkt[pos] = (unsigned short)b;
    }
    __syncthreads();
    for (int i = t; i < n; i += 256) {
        int b = bkt[i];
        pairbuf[gbase[b] + (i - lbase[b])] = sorted[i];
    }
}

// ---------- fused: per-node degree (LDS) -> offs + dinv + CSR placement ----------
__global__ __launch_bounds__(256) void k_offs_place(
    const unsigned* __restrict__ pairbuf, const int* __restrict__ bbase,
    int* __restrict__ offs, float* __restrict__ dinv, int* __restrict__ csr) {
    __shared__ int dcnt[256];
    __shared__ int p[256];
    __shared__ int lcur[256];
    int t = threadIdx.x;
    int b = blockIdx.x;
    int base = bbase[b];
    int cnt = bbase[b + 1] - base;
    int node0 = b << 8;
    dcnt[t] = 0;
    __syncthreads();
    for (int i = t; i < cnt; i += 256)
        atomicAdd(&dcnt[pairbuf[base + i] >> 24], 1);
    __syncthreads();
    int v = dcnt[t];
    p[t] = v;
    __syncthreads();
    for (int d = 1; d < 256; d <<= 1) {
        int u = (t >= d) ? p[t - d] : 0;
        __syncthreads();
        p[t] += u;
        __syncthreads();
    }
    int ex = p[t] - v;           // exclusive within-bucket prefix
    lcur[t] = ex;
    int node = node0 + t;
    if (node <= NN) offs[node] = base + ex;  // node==NN -> NE exactly
    if (node < NN) dinv[node] = rsqrtf((float)(v + 1));
    __syncthreads();
    for (int i = t; i < cnt; i += 256) {
        unsigned e = pairbuf[base + i];
        int slot = atomicAdd(&lcur[e >> 24], 1);
        csr[base + slot] = (int)(e & 0xFFFFFFu);
    }
}

// ---------- W [128][FOUT] fp32 -> Wt [FOUT][128] fp16 (transpose+cast) ----------
__global__ void k_wt(const float* __restrict__ W, __half* __restrict__ Wt, int fout) {
    int idx = blockIdx.x * 256 + threadIdx.x;
    if (idx < 128 * fout) {
        int k = idx / fout, n = idx % fout;
        Wt[n * 128 + k] = __float2half(W[idx]);
    }
}

// ---------- MFMA matmul: Out = fp16( dinv ⊙ (X @ W) ) row-major, K=128 ----------
template <int FOUT, bool HALF_IN>
__global__ __launch_bounds__(256) void k_mm_mfma(const void* __restrict__ Xv,
                                                 const __half* __restrict__ Wt,
                                                 const float* __restrict__ dinv,
                                                 __half* __restrict__ Out) {
    constexpr int PITCH = 136;
    __shared__ _Float16 Xs[64 * PITCH];
    __shared__ _Float16 Ws[FOUT * PITCH];
    int t = threadIdx.x;
    int row0 = blockIdx.x * 64;

    if (HALF_IN) {
        const __half* X = (const __half*)Xv;
        for (int i = t; i < 64 * 16; i += 256) {
            int r = i >> 4, kg = i & 15;
            int row = row0 + r;
            half8 v = {};
            if (row < NN) v = *(const half8*)(X + (size_t)row * 128 + kg * 8);
            *(half8*)(Xs + r * PITCH + kg * 8) = v;
        }
    } else {
        const float* X = (const float*)Xv;
        for (int i = t; i < 64 * 32; i += 256) {
            int r = i >> 5, f4 = i & 31;
            int row = row0 + r;
            half4v h = {};
            if (row < NN) {
                float4 v = *(const float4*)(X + (size_t)row * 128 + f4 * 4);
                h[0] = (_Float16)v.x; h[1] = (_Float16)v.y;
                h[2] = (_Float16)v.z; h[3] = (_Float16)v.w;
            }
            *(half4v*)(Xs + r * PITCH + f4 * 4) = h;
        }
    }
    for (int i = t; i < FOUT * 16; i += 256) {
        int n = i >> 4, kg = i & 15;
        *(half8*)(Ws + n * PITCH + kg * 8) = *(const half8*)(Wt + n * 128 + kg * 8);
    }
    __syncthreads();

    int wave = t >> 6, lane = t & 63;
    int m = lane & 15, quad = lane >> 4;
    int wrow = wave * 16;
    constexpr int NCT = FOUT / 16;
    floatx4 acc[NCT];
#pragma unroll
    for (int c = 0; c < NCT; ++c) acc[c] = (floatx4){0.f, 0.f, 0.f, 0.f};

#pragma unroll
    for (int kc = 0; kc < 4; ++kc) {
        half8 a = *(const half8*)(Xs + (wrow + m) * PITCH + kc * 32 + quad * 8);
#pragma unroll
        for (int c = 0; c < NCT; ++c) {
            half8 b = *(const half8*)(Ws + (c * 16 + m) * PITCH + kc * 32 + quad * 8);
            acc[c] = __builtin_amdgcn_mfma_f32_16x16x32_f16(a, b, acc[c], 0, 0, 0);
        }
    }

    float dv[4];
    int rowb = row0 + wrow + quad * 4;
#pragma unroll
    for (int r = 0; r < 4; ++r) dv[r] = (rowb + r < NN) ? dinv[rowb + r] : 0.f;
#pragma unroll
    for (int c = 0; c < NCT; ++c) {
#pragma unroll
        for (int r = 0; r < 4; ++r) {
            int row = rowb + r;
            if (row < NN)
                Out[(size_t)row * FOUT + c * 16 + m] = __float2half(acc[c][r] * dv[r]);
        }
    }
}

// ---------- aggregation: lane = 16 B (8 fp16 features); multiple nodes per wave ----------
// 8-deep unroll: 8 independent 16 B gathers in flight per lane (MLP-bound kernel).
template <int FOUT, bool RELU>
__global__ __launch_bounds__(256) void k_agg(
    const __half* __restrict__ G, const int* __restrict__ csr,
    const int* __restrict__ offs, const float* __restrict__ dinv,
    const float* __restrict__ bias, void* __restrict__ OutV) {
    constexpr int LPN = FOUT / 8;   // lanes per node
    constexpr int NPW = 64 / LPN;   // nodes per wave
    int t = threadIdx.x;
    int wave = t >> 6, lane = t & 63;
    int sub = lane / LPN, fl = lane % LPN;
    int node = (blockIdx.x * 4 + wave) * NPW + sub;
    if (node >= NN) return;
    const _Float16* g = (const _Float16*)G;
    float acc[8];
    {
        half8 v = *(const half8*)(g + (size_t)node * FOUT + fl * 8);  // self loop
#pragma unroll
        for (int j = 0; j < 8; ++j) acc[j] = (float)v[j];
    }
    int e0 = offs[node], e1 = offs[node + 1];
    int e = e0;
    for (; e + 8 <= e1; e += 8) {   // 8 independent 16 B gathers in flight
        int s[8];
#pragma unroll
        for (int q = 0; q < 8; ++q) s[q] = csr[e + q];
        half8 v[8];
#pragma unroll
        for (int q = 0; q < 8; ++q)
            v[q] = *(const half8*)(g + (size_t)s[q] * FOUT + fl * 8);
#pragma unroll
        for (int j = 0; j < 8; ++j)
            acc[j] += (((float)v[0][j] + (float)v[1][j]) + ((float)v[2][j] + (float)v[3][j]))
                    + (((float)v[4][j] + (float)v[5][j]) + ((float)v[6][j] + (float)v[7][j]));
    }
    for (; e + 4 <= e1; e += 4) {
        int s0 = csr[e], s1 = csr[e + 1], s2 = csr[e + 2], s3 = csr[e + 3];
        half8 v0 = *(const half8*)(g + (size_t)s0 * FOUT + fl * 8);
        half8 v1 = *(const half8*)(g + (size_t)s1 * FOUT + fl * 8);
        half8 v2 = *(const half8*)(g + (size_t)s2 * FOUT + fl * 8);
        half8 v3 = *(const half8*)(g + (size_t)s3 * FOUT + fl * 8);
#pragma unroll
        for (int j = 0; j < 8; ++j)
            acc[j] += ((float)v0[j] + (float)v1[j]) + ((float)v2[j] + (float)v3[j]);
    }
    for (; e < e1; ++e) {
        half8 v = *(const half8*)(g + (size_t)csr[e] * FOUT + fl * 8);
#pragma unroll
        for (int j = 0; j < 8; ++j) acc[j] += (float)v[j];
    }
    float di = dinv[node];
    float4 b0 = *(const float4*)(bias + fl * 8);
    float4 b1 = *(const float4*)(bias + fl * 8 + 4);
    float o[8];
    o[0] = acc[0] * di + b0.x; o[1] = acc[1] * di + b0.y;
    o[2] = acc[2] * di + b0.z; o[3] = acc[3] * di + b0.w;
    o[4] = acc[4] * di + b1.x; o[5] = acc[5] * di + b1.y;
    o[6] = acc[6] * di + b1.z; o[7] = acc[7] * di + b1.w;
    if (RELU) {
        half8 h;
#pragma unroll
        for (int j = 0; j < 8; ++j) h[j] = (_Float16)fmaxf(o[j], 0.f);
        *(half8*)((__half*)OutV + (size_t)node * FOUT + fl * 8) = h;
    } else {
        float* Out = (float*)OutV + (size_t)node * FOUT + fl * 8;
        *(float4*)Out = make_float4(o[0], o[1], o[2], o[3]);
        *(float4*)(Out + 4) = make_float4(o[4], o[5], o[6], o[7]);
    }
}

// ---------- mean pool: 1 block/graph, 256 thr = 64 features x 4 row-slices ----------
__global__ __launch_bounds__(256) void k_pool(const float* __restrict__ H,
                                              const int* __restrict__ batch,
                                              float* __restrict__ out) {
    __shared__ float red[256];
    int gph = blockIdx.x;
    int lo = 0, hi = NN;
    while (lo < hi) { int m = (lo + hi) >> 1; if (batch[m] < gph) lo = m + 1; else hi = m; }
    int s0 = lo;
    hi = NN;
    while (lo < hi) { int m = (lo + hi) >> 1; if (batch[m] <= gph) lo = m + 1; else hi = m; }
    int s1 = lo;
    int t = threadIdx.x;
    int f = t & 63, rw = t >> 6;
    float s = 0.f;
    for (int n = s0 + rw; n < s1; n += 4) s += H[(size_t)n * 64 + f];
    red[t] = s;
    __syncthreads();
    if (rw == 0) {
        float tot = (red[f] + red[64 + f]) + (red[128 + f] + red[192 + f]);
        int cnt = s1 - s0;
        out[gph * 64 + f] = (cnt > 0) ? tot / (float)cnt : 0.f;
    }
}

extern "C" void kernel_launch(void* const* d_in, const int* in_sizes, int n_in,
                              void* d_out, int out_size, void* d_ws, size_t ws_size,
                              hipStream_t stream) {
    const float* x     = (const float*)d_in[0];
    const int*   ei    = (const int*)d_in[1];   // [2, NE] int32
    const int*   batch = (const int*)d_in[2];
    const float* W1    = (const float*)d_in[3];
    const float* b1    = (const float*)d_in[4];
    const float* W2    = (const float*)d_in[5];
    const float* b2    = (const float*)d_in[6];
    const int* esrc = ei;
    const int* edst = ei + NE;

    char* ws = (char*)d_ws;
    size_t off = 0;
    __half* G1  = (__half*)(ws + off); off += (size_t)NN * 128 * 2;  // fp16 row-major
    __half* G2  = (__half*)(ws + off); off += (size_t)NN * 64 * 2;   // fp16 row-major
    __half* B   = (__half*)(ws + off); off += (size_t)NN * 128 * 2;  // fp16 row-major
    float* AGG2 = (float*)(ws + off);  off += (size_t)NN * 64 * 4;   // fp32 row-major
    int*   csr  = (int*)(ws + off);    off += (size_t)NE * 4;
    unsigned* pairbuf = (unsigned*)(ws + off); off += (size_t)NE * 4;
    int*   offs = (int*)(ws + off);    off += ((size_t)NN + 8) * 4;
    float* dinv = (float*)(ws + off);  off += (size_t)NN * 4;
    int*   bcnt = (int*)(ws + off);    off += 512 * 4;
    int*   bbase= (int*)(ws + off);    off += 512 * 4;
    int*   gcur = (int*)(ws + off);    off += 512 * 4;
    __half* Wt1 = (__half*)(ws + off); off += 128 * 128 * 2;
    __half* Wt2 = (__half*)(ws + off); off += 128 * 64 * 2;

    // CSR build: bucket hist -> scan -> sort -> fused offs/dinv/place
    hipMemsetAsync(bcnt, 0, 512 * sizeof(int), stream);
    k_bhist<<<NHB, 256, 0, stream>>>(edst, bcnt);
    k_bscan<<<1, 512, 0, stream>>>(bcnt, bbase, gcur);
    k_csort<<<NCB, 256, 0, stream>>>(esrc, edst, gcur, pairbuf);
    k_offs_place<<<NBLK, 256, 0, stream>>>(pairbuf, bbase, offs, dinv, csr);

    // weight transpose+cast (tiny)
    k_wt<<<64, 256, 0, stream>>>(W1, Wt1, 128);
    k_wt<<<32, 256, 0, stream>>>(W2, Wt2, 64);

    const int MMB = (NN + 63) / 64;
    // layer 1: G1 = fp16(dinv ⊙ (x @ W1));  B = fp16(relu(dinv ⊙ csr_sum(G1) + b1))
    k_mm_mfma<128, false><<<MMB, 256, 0, stream>>>(x, Wt1, dinv, G1);
    k_agg<128, true><<<(NN + 15) / 16, 256, 0, stream>>>(G1, csr, offs, dinv, b1, B);
    // layer 2: G2 = fp16(dinv ⊙ (B @ W2));  AGG2 = dinv ⊙ csr_sum(G2) + b2
    k_mm_mfma<64, true><<<MMB, 256, 0, stream>>>(B, Wt2, dinv, G2);
    k_agg<64, false><<<(NN + 31) / 32, 256, 0, stream>>>(G2, csr, offs, dinv, b2, AGG2);

    k_pool<<<NG, 256, 0, stream>>>(AGG2, batch, (float*)d_out);
}

// Round 15
// 322.513 us; speedup vs baseline: 1.0222x; 1.0222x over previous
//
#include <hip/hip_runtime.h>
#include <hip/hip_fp16.h>

#define NN 100000   // nodes
#define NE 1600000  // edges
#define NG 512      // graphs
#define NBLK 391    // ceil(NN/256) = coarse buckets (dst>>8), 256 nodes each
#define EPB 8192    // edges per batch block
#define NCB 196     // ceil(NE/EPB)
// IN=128, HID=128, OUT=64

typedef _Float16 half8 __attribute__((ext_vector_type(8)));
typedef _Float16 half4v __attribute__((ext_vector_type(4)));
typedef float floatx4 __attribute__((ext_vector_type(4)));

// ---------- bucket histogram: LDS-privatized, 391 global atomics per block ----------
__global__ __launch_bounds__(256) void k_bhist(const int* __restrict__ dst,
                                               int* __restrict__ bcnt) {
    __shared__ int h[NBLK];
    int t = threadIdx.x;
    for (int i = t; i < NBLK; i += 256) h[i] = 0;
    __syncthreads();
    int e0 = blockIdx.x * EPB;
    int e1 = e0 + EPB; if (e1 > NE) e1 = NE;
    for (int i = e0 + t; i < e1; i += 256) atomicAdd(&h[dst[i] >> 8], 1);
    __syncthreads();
    for (int i = t; i < NBLK; i += 256)
        if (h[i]) atomicAdd(&bcnt[i], h[i]);
}

// ---------- scan bucket counts -> bucket bases + csort cursors ----------
__global__ __launch_bounds__(512) void k_bscan(const int* __restrict__ bcnt,
                                               int* __restrict__ bbase,
                                               int* __restrict__ gcur) {
    __shared__ int s[512];
    int t = threadIdx.x;
    int v = (t < NBLK) ? bcnt[t] : 0;
    s[t] = v;
    __syncthreads();
    for (int d = 1; d < 512; d <<= 1) {
        int u = (t >= d) ? s[t - d] : 0;
        __syncthreads();
        s[t] += u;
        __syncthreads();
    }
    if (t < NBLK) {
        int ex = s[t] - v;
        bbase[t] = ex;
        gcur[t] = ex;
    }
    if (t == 0) bbase[NBLK] = NE;
}

// ---------- batch counting-sort edges into coarse-bucket regions ----------
__global__ __launch_bounds__(256) void k_csort(const int* __restrict__ src,
                                               const int* __restrict__ dst,
                                               int* __restrict__ gcur,
                                               unsigned* __restrict__ pairbuf) {
    __shared__ int hcnt[NBLK];
    __shared__ int lbase[NBLK];
    __shared__ int lcur[NBLK];
    __shared__ int gbase[NBLK];
    __shared__ int ss[512];
    __shared__ unsigned sorted[EPB];
    __shared__ unsigned short bkt[EPB];
    int t = threadIdx.x;
    int e0 = blockIdx.x * EPB;
    int e1 = e0 + EPB; if (e1 > NE) e1 = NE;
    int n = e1 - e0;

    for (int i = t; i < NBLK; i += 256) hcnt[i] = 0;
    __syncthreads();
    for (int i = e0 + t; i < e1; i += 256)
        atomicAdd(&hcnt[dst[i] >> 8], 1);
    __syncthreads();
    ss[t]       = (t < NBLK) ? hcnt[t] : 0;
    ss[t + 256] = (t + 256 < NBLK) ? hcnt[t + 256] : 0;
    __syncthreads();
    for (int d = 1; d < 512; d <<= 1) {
        int v1 = (t >= d) ? ss[t - d] : 0;
        int v2 = ss[t + 256 - d];
        __syncthreads();
        ss[t] += v1; ss[t + 256] += v2;
        __syncthreads();
    }
    for (int i = t; i < NBLK; i += 256) {
        int ex = ss[i] - hcnt[i];
        lbase[i] = ex;
        lcur[i] = ex;
        if (hcnt[i] > 0) gbase[i] = atomicAdd(&gcur[i], hcnt[i]);
    }
    __syncthreads();
    for (int i = e0 + t; i < e1; i += 256) {
        int d = dst[i];
        int b = d >> 8;
        int pos = atomicAdd(&lcur[b], 1);
        sorted[pos] = ((unsigned)(d & 255) << 24) | (unsigned)src[i];
        bkt[pos] = (unsigned short)b;
    }
    __syncthreads();
    for (int i = t; i < n; i += 256) {
        int b = bkt[i];
        pairbuf[gbase[b] + (i - lbase[b])] = sorted[i];
    }
}

// ---------- fused: per-node degree (LDS) -> offs + dinv + CSR placement ----------
__global__ __launch_bounds__(256) void k_offs_place(
    const unsigned* __restrict__ pairbuf, const int* __restrict__ bbase,
    int* __restrict__ offs, float* __restrict__ dinv, int* __restrict__ csr) {
    __shared__ int dcnt[256];
    __shared__ int p[256];
    __shared__ int lcur[256];
    int t = threadIdx.x;
    int b = blockIdx.x;
    int base = bbase[b];
    int cnt = bbase[b + 1] - base;
    int node0 = b << 8;
    dcnt[t] = 0;
    __syncthreads();
    for (int i = t; i < cnt; i += 256)
        atomicAdd(&dcnt[pairbuf[base + i] >> 24], 1);
    __syncthreads();
    int v = dcnt[t];
    p[t] = v;
    __syncthreads();
    for (int d = 1; d < 256; d <<= 1) {
        int u = (t >= d) ? p[t - d] : 0;
        __syncthreads();
        p[t] += u;
        __syncthreads();
    }
    int ex = p[t] - v;           // exclusive within-bucket prefix
    lcur[t] = ex;
    int node = node0 + t;
    if (node <= NN) offs[node] = base + ex;  // node==NN -> NE exactly
    if (node < NN) dinv[node] = rsqrtf((float)(v + 1));
    __syncthreads();
    for (int i = t; i < cnt; i += 256) {
        unsigned e = pairbuf[base + i];
        int slot = atomicAdd(&lcur[e >> 24], 1);
        csr[base + slot] = (int)(e & 0xFFFFFFu);
    }
}

// ---------- W [128][FOUT] fp32 -> Wt [FOUT][128] fp16 (transpose+cast) ----------
__global__ void k_wt(const float* __restrict__ W, __half* __restrict__ Wt, int fout) {
    int idx = blockIdx.x * 256 + threadIdx.x;
    if (idx < 128 * fout) {
        int k = idx / fout, n = idx % fout;
        Wt[n * 128 + k] = __float2half(W[idx]);
    }
}

// ---------- MFMA matmul: Out = fp16( dinv ⊙ (X @ W) ) row-major, K=128 ----------
template <int FOUT, bool HALF_IN>
__global__ __launch_bounds__(256) void k_mm_mfma(const void* __restrict__ Xv,
                                                 const __half* __restrict__ Wt,
                                                 const float* __restrict__ dinv,
                                                 __half* __restrict__ Out) {
    constexpr int PITCH = 136;
    __shared__ _Float16 Xs[64 * PITCH];
    __shared__ _Float16 Ws[FOUT * PITCH];
    int t = threadIdx.x;
    int row0 = blockIdx.x * 64;

    if (HALF_IN) {
        const __half* X = (const __half*)Xv;
        for (int i = t; i < 64 * 16; i += 256) {
            int r = i >> 4, kg = i & 15;
            int row = row0 + r;
            half8 v = {};
            if (row < NN) v = *(const half8*)(X + (size_t)row * 128 + kg * 8);
            *(half8*)(Xs + r * PITCH + kg * 8) = v;
        }
    } else {
        const float* X = (const float*)Xv;
        for (int i = t; i < 64 * 32; i += 256) {
            int r = i >> 5, f4 = i & 31;
            int row = row0 + r;
            half4v h = {};
            if (row < NN) {
                float4 v = *(const float4*)(X + (size_t)row * 128 + f4 * 4);
                h[0] = (_Float16)v.x; h[1] = (_Float16)v.y;
                h[2] = (_Float16)v.z; h[3] = (_Float16)v.w;
            }
            *(half4v*)(Xs + r * PITCH + f4 * 4) = h;
        }
    }
    for (int i = t; i < FOUT * 16; i += 256) {
        int n = i >> 4, kg = i & 15;
        *(half8*)(Ws + n * PITCH + kg * 8) = *(const half8*)(Wt + n * 128 + kg * 8);
    }
    __syncthreads();

    int wave = t >> 6, lane = t & 63;
    int m = lane & 15, quad = lane >> 4;
    int wrow = wave * 16;
    constexpr int NCT = FOUT / 16;
    floatx4 acc[NCT];
#pragma unroll
    for (int c = 0; c < NCT; ++c) acc[c] = (floatx4){0.f, 0.f, 0.f, 0.f};

#pragma unroll
    for (int kc = 0; kc < 4; ++kc) {
        half8 a = *(const half8*)(Xs + (wrow + m) * PITCH + kc * 32 + quad * 8);
#pragma unroll
        for (int c = 0; c < NCT; ++c) {
            half8 b = *(const half8*)(Ws + (c * 16 + m) * PITCH + kc * 32 + quad * 8);
            acc[c] = __builtin_amdgcn_mfma_f32_16x16x32_f16(a, b, acc[c], 0, 0, 0);
        }
    }

    float dv[4];
    int rowb = row0 + wrow + quad * 4;
#pragma unroll
    for (int r = 0; r < 4; ++r) dv[r] = (rowb + r < NN) ? dinv[rowb + r] : 0.f;
#pragma unroll
    for (int c = 0; c < NCT; ++c) {
#pragma unroll
        for (int r = 0; r < 4; ++r) {
            int row = rowb + r;
            if (row < NN)
                Out[(size_t)row * FOUT + c * 16 + m] = __float2half(acc[c][r] * dv[r]);
        }
    }
}

// ---------- aggregation: lane = 16 B (8 fp16 features); multiple nodes per wave ----------
template <int FOUT, bool RELU>
__global__ __launch_bounds__(256) void k_agg(
    const __half* __restrict__ G, const int* __restrict__ csr,
    const int* __restrict__ offs, const float* __restrict__ dinv,
    const float* __restrict__ bias, void* __restrict__ OutV) {
    constexpr int LPN = FOUT / 8;   // lanes per node
    constexpr int NPW = 64 / LPN;   // nodes per wave
    int t = threadIdx.x;
    int wave = t >> 6, lane = t & 63;
    int sub = lane / LPN, fl = lane % LPN;
    int node = (blockIdx.x * 4 + wave) * NPW + sub;
    if (node >= NN) return;
    const _Float16* g = (const _Float16*)G;
    float acc[8];
    {
        half8 v = *(const half8*)(g + (size_t)node * FOUT + fl * 8);  // self loop
#pragma unroll
        for (int j = 0; j < 8; ++j) acc[j] = (float)v[j];
    }
    int e0 = offs[node], e1 = offs[node + 1];
    int e = e0;
    for (; e + 4 <= e1; e += 4) {   // 4 independent 16 B gathers in flight
        int s0 = csr[e], s1 = csr[e + 1], s2 = csr[e + 2], s3 = csr[e + 3];
        half8 v0 = *(const half8*)(g + (size_t)s0 * FOUT + fl * 8);
        half8 v1 = *(const half8*)(g + (size_t)s1 * FOUT + fl * 8);
        half8 v2 = *(const half8*)(g + (size_t)s2 * FOUT + fl * 8);
        half8 v3 = *(const half8*)(g + (size_t)s3 * FOUT + fl * 8);
#pragma unroll
        for (int j = 0; j < 8; ++j)
            acc[j] += ((float)v0[j] + (float)v1[j]) + ((float)v2[j] + (float)v3[j]);
    }
    for (; e < e1; ++e) {
        half8 v = *(const half8*)(g + (size_t)csr[e] * FOUT + fl * 8);
#pragma unroll
        for (int j = 0; j < 8; ++j) acc[j] += (float)v[j];
    }
    float di = dinv[node];
    float4 b0 = *(const float4*)(bias + fl * 8);
    float4 b1 = *(const float4*)(bias + fl * 8 + 4);
    float o[8];
    o[0] = acc[0] * di + b0.x; o[1] = acc[1] * di + b0.y;
    o[2] = acc[2] * di + b0.z; o[3] = acc[3] * di + b0.w;
    o[4] = acc[4] * di + b1.x; o[5] = acc[5] * di + b1.y;
    o[6] = acc[6] * di + b1.z; o[7] = acc[7] * di + b1.w;
    if (RELU) {
        half8 h;
#pragma unroll
        for (int j = 0; j < 8; ++j) h[j] = (_Float16)fmaxf(o[j], 0.f);
        *(half8*)((__half*)OutV + (size_t)node * FOUT + fl * 8) = h;
    } else {
        float* Out = (float*)OutV + (size_t)node * FOUT + fl * 8;
        *(float4*)Out = make_float4(o[0], o[1], o[2], o[3]);
        *(float4*)(Out + 4) = make_float4(o[4], o[5], o[6], o[7]);
    }
}

// ---------- mean pool: 1 block/graph, 256 thr = 64 features x 4 row-slices ----------
__global__ __launch_bounds__(256) void k_pool(const float* __restrict__ H,
                                              const int* __restrict__ batch,
                                              float* __restrict__ out) {
    __shared__ float red[256];
    int gph = blockIdx.x;
    int lo = 0, hi = NN;
    while (lo < hi) { int m = (lo + hi) >> 1; if (batch[m] < gph) lo = m + 1; else hi = m; }
    int s0 = lo;
    hi = NN;
    while (lo < hi) { int m = (lo + hi) >> 1; if (batch[m] <= gph) lo = m + 1; else hi = m; }
    int s1 = lo;
    int t = threadIdx.x;
    int f = t & 63, rw = t >> 6;
    float s = 0.f;
    for (int n = s0 + rw; n < s1; n += 4) s += H[(size_t)n * 64 + f];
    red[t] = s;
    __syncthreads();
    if (rw == 0) {
        float tot = (red[f] + red[64 + f]) + (red[128 + f] + red[192 + f]);
        int cnt = s1 - s0;
        out[gph * 64 + f] = (cnt > 0) ? tot / (float)cnt : 0.f;
    }
}

extern "C" void kernel_launch(void* const* d_in, const int* in_sizes, int n_in,
                              void* d_out, int out_size, void* d_ws, size_t ws_size,
                              hipStream_t stream) {
    const float* x     = (const float*)d_in[0];
    const int*   ei    = (const int*)d_in[1];   // [2, NE] int32
    const int*   batch = (const int*)d_in[2];
    const float* W1    = (const float*)d_in[3];
    const float* b1    = (const float*)d_in[4];
    const float* W2    = (const float*)d_in[5];
    const float* b2    = (const float*)d_in[6];
    const int* esrc = ei;
    const int* edst = ei + NE;

    char* ws = (char*)d_ws;
    size_t off = 0;
    __half* G1  = (__half*)(ws + off); off += (size_t)NN * 128 * 2;  // fp16 row-major
    __half* G2  = (__half*)(ws + off); off += (size_t)NN * 64 * 2;   // fp16 row-major
    __half* B   = (__half*)(ws + off); off += (size_t)NN * 128 * 2;  // fp16 row-major
    float* AGG2 = (float*)(ws + off);  off += (size_t)NN * 64 * 4;   // fp32 row-major
    int*   csr  = (int*)(ws + off);    off += (size_t)NE * 4;
    unsigned* pairbuf = (unsigned*)(ws + off); off += (size_t)NE * 4;
    int*   offs = (int*)(ws + off);    off += ((size_t)NN + 8) * 4;
    float* dinv = (float*)(ws + off);  off += (size_t)NN * 4;
    int*   bcnt = (int*)(ws + off);    off += 512 * 4;
    int*   bbase= (int*)(ws + off);    off += 512 * 4;
    int*   gcur = (int*)(ws + off);    off += 512 * 4;
    __half* Wt1 = (__half*)(ws + off); off += 128 * 128 * 2;
    __half* Wt2 = (__half*)(ws + off); off += 128 * 64 * 2;

    // CSR build: bucket hist -> scan -> sort -> fused offs/dinv/place
    hipMemsetAsync(bcnt, 0, 512 * sizeof(int), stream);
    k_bhist<<<NCB, 256, 0, stream>>>(edst, bcnt);
    k_bscan<<<1, 512, 0, stream>>>(bcnt, bbase, gcur);
    k_csort<<<NCB, 256, 0, stream>>>(esrc, edst, gcur, pairbuf);
    k_offs_place<<<NBLK, 256, 0, stream>>>(pairbuf, bbase, offs, dinv, csr);

    // weight transpose+cast (tiny)
    k_wt<<<64, 256, 0, stream>>>(W1, Wt1, 128);
    k_wt<<<32, 256, 0, stream>>>(W2, Wt2, 64);

    const int MMB = (NN + 63) / 64;
    // layer 1: G1 = fp16(dinv ⊙ (x @ W1));  B = fp16(relu(dinv ⊙ csr_sum(G1) + b1))
    k_mm_mfma<128, false><<<MMB, 256, 0, stream>>>(x, Wt1, dinv, G1);
    k_agg<128, true><<<(NN + 15) / 16, 256, 0, stream>>>(G1, csr, offs, dinv, b1, B);
    // layer 2: G2 = fp16(dinv ⊙ (B @ W2));  AGG2 = dinv ⊙ csr_sum(G2) + b2
    k_mm_mfma<64, true><<<MMB, 256, 0, stream>>>(B, Wt2, dinv, G2);
    k_agg<64, false><<<(NN + 31) / 32, 256, 0, stream>>>(G2, csr, offs, dinv, b2, AGG2);

    k_pool<<<NG, 256, 0, stream>>>(AGG2, batch, (float*)d_out);
}

// Round 16
// 307.234 us; speedup vs baseline: 1.0731x; 1.0497x over previous
//
#include <hip/hip_runtime.h>
#include <hip/hip_fp16.h>

#define NN 100000   // nodes
#define NE 1600000  // edges
#define NG 512      // graphs
#define NBLK 391    // ceil(NN/256) = coarse buckets (dst>>8), 256 nodes each
#define EPB 8192    // edges per batch block
#define NCB 196     // ceil(NE/EPB)
// IN=128, HID=128, OUT=64

typedef _Float16 half8 __attribute__((ext_vector_type(8)));
typedef _Float16 half4v __attribute__((ext_vector_type(4)));
typedef float floatx4 __attribute__((ext_vector_type(4)));

// ---------- bucket histogram: LDS-privatized, 391 global atomics per block ----------
__global__ __launch_bounds__(256) void k_bhist(const int* __restrict__ dst,
                                               int* __restrict__ bcnt) {
    __shared__ int h[NBLK];
    int t = threadIdx.x;
    for (int i = t; i < NBLK; i += 256) h[i] = 0;
    __syncthreads();
    int e0 = blockIdx.x * EPB;
    int e1 = e0 + EPB; if (e1 > NE) e1 = NE;
    for (int i = e0 + t; i < e1; i += 256) atomicAdd(&h[dst[i] >> 8], 1);
    __syncthreads();
    for (int i = t; i < NBLK; i += 256)
        if (h[i]) atomicAdd(&bcnt[i], h[i]);
}

// ---------- scan bucket counts -> bucket bases + csort cursors ----------
__global__ __launch_bounds__(512) void k_bscan(const int* __restrict__ bcnt,
                                               int* __restrict__ bbase,
                                               int* __restrict__ gcur) {
    __shared__ int s[512];
    int t = threadIdx.x;
    int v = (t < NBLK) ? bcnt[t] : 0;
    s[t] = v;
    __syncthreads();
    for (int d = 1; d < 512; d <<= 1) {
        int u = (t >= d) ? s[t - d] : 0;
        __syncthreads();
        s[t] += u;
        __syncthreads();
    }
    if (t < NBLK) {
        int ex = s[t] - v;
        bbase[t] = ex;
        gcur[t] = ex;
    }
    if (t == 0) bbase[NBLK] = NE;
}

// ---------- batch counting-sort edges into coarse-bucket regions ----------
__global__ __launch_bounds__(256) void k_csort(const int* __restrict__ src,
                                               const int* __restrict__ dst,
                                               int* __restrict__ gcur,
                                               unsigned* __restrict__ pairbuf) {
    __shared__ int hcnt[NBLK];
    __shared__ int lbase[NBLK];
    __shared__ int lcur[NBLK];
    __shared__ int gbase[NBLK];
    __shared__ int ss[512];
    __shared__ unsigned sorted[EPB];
    __shared__ unsigned short bkt[EPB];
    int t = threadIdx.x;
    int e0 = blockIdx.x * EPB;
    int e1 = e0 + EPB; if (e1 > NE) e1 = NE;
    int n = e1 - e0;

    for (int i = t; i < NBLK; i += 256) hcnt[i] = 0;
    __syncthreads();
    for (int i = e0 + t; i < e1; i += 256)
        atomicAdd(&hcnt[dst[i] >> 8], 1);
    __syncthreads();
    ss[t]       = (t < NBLK) ? hcnt[t] : 0;
    ss[t + 256] = (t + 256 < NBLK) ? hcnt[t + 256] : 0;
    __syncthreads();
    for (int d = 1; d < 512; d <<= 1) {
        int v1 = (t >= d) ? ss[t - d] : 0;
        int v2 = ss[t + 256 - d];
        __syncthreads();
        ss[t] += v1; ss[t + 256] += v2;
        __syncthreads();
    }
    for (int i = t; i < NBLK; i += 256) {
        int ex = ss[i] - hcnt[i];
        lbase[i] = ex;
        lcur[i] = ex;
        if (hcnt[i] > 0) gbase[i] = atomicAdd(&gcur[i], hcnt[i]);
    }
    __syncthreads();
    for (int i = e0 + t; i < e1; i += 256) {
        int d = dst[i];
        int b = d >> 8;
        int pos = atomicAdd(&lcur[b], 1);
        sorted[pos] = ((unsigned)(d & 255) << 24) | (unsigned)src[i];
        bkt[pos] = (unsigned short)b;
    }
    __syncthreads();
    for (int i = t; i < n; i += 256) {
        int b = bkt[i];
        pairbuf[gbase[b] + (i - lbase[b])] = sorted[i];
    }
}

// ---------- fused: per-node degree (LDS) -> offs + dinv + CSR placement ----------
__global__ __launch_bounds__(256) void k_offs_place(
    const unsigned* __restrict__ pairbuf, const int* __restrict__ bbase,
    int* __restrict__ offs, float* __restrict__ dinv, int* __restrict__ csr) {
    __shared__ int dcnt[256];
    __shared__ int p[256];
    __shared__ int lcur[256];
    int t = threadIdx.x;
    int b = blockIdx.x;
    int base = bbase[b];
    int cnt = bbase[b + 1] - base;
    int node0 = b << 8;
    dcnt[t] = 0;
    __syncthreads();
    for (int i = t; i < cnt; i += 256)
        atomicAdd(&dcnt[pairbuf[base + i] >> 24], 1);
    __syncthreads();
    int v = dcnt[t];
    p[t] = v;
    __syncthreads();
    for (int d = 1; d < 256; d <<= 1) {
        int u = (t >= d) ? p[t - d] : 0;
        __syncthreads();
        p[t] += u;
        __syncthreads();
    }
    int ex = p[t] - v;           // exclusive within-bucket prefix
    lcur[t] = ex;
    int node = node0 + t;
    if (node <= NN) offs[node] = base + ex;  // node==NN -> NE exactly
    if (node < NN) dinv[node] = rsqrtf((float)(v + 1));
    __syncthreads();
    for (int i = t; i < cnt; i += 256) {
        unsigned e = pairbuf[base + i];
        int slot = atomicAdd(&lcur[e >> 24], 1);
        csr[base + slot] = (int)(e & 0xFFFFFFu);
    }
}

// ---------- W [128][FOUT] fp32 -> Wt [FOUT][128] fp16 (transpose+cast) ----------
__global__ void k_wt(const float* __restrict__ W, __half* __restrict__ Wt, int fout) {
    int idx = blockIdx.x * 256 + threadIdx.x;
    if (idx < 128 * fout) {
        int k = idx / fout, n = idx % fout;
        Wt[n * 128 + k] = __float2half(W[idx]);
    }
}

// ---------- MFMA matmul: Out = fp16( dinv ⊙ (X @ W) ) row-major, K=128 ----------
template <int FOUT, bool HALF_IN>
__global__ __launch_bounds__(256) void k_mm_mfma(const void* __restrict__ Xv,
                                                 const __half* __restrict__ Wt,
                                                 const float* __restrict__ dinv,
                                                 __half* __restrict__ Out) {
    constexpr int PITCH = 136;
    __shared__ _Float16 Xs[64 * PITCH];
    __shared__ _Float16 Ws[FOUT * PITCH];
    int t = threadIdx.x;
    int row0 = blockIdx.x * 64;

    if (HALF_IN) {
        const __half* X = (const __half*)Xv;
        for (int i = t; i < 64 * 16; i += 256) {
            int r = i >> 4, kg = i & 15;
            int row = row0 + r;
            half8 v = {};
            if (row < NN) v = *(const half8*)(X + (size_t)row * 128 + kg * 8);
            *(half8*)(Xs + r * PITCH + kg * 8) = v;
        }
    } else {
        const float* X = (const float*)Xv;
        for (int i = t; i < 64 * 32; i += 256) {
            int r = i >> 5, f4 = i & 31;
            int row = row0 + r;
            half4v h = {};
            if (row < NN) {
                float4 v = *(const float4*)(X + (size_t)row * 128 + f4 * 4);
                h[0] = (_Float16)v.x; h[1] = (_Float16)v.y;
                h[2] = (_Float16)v.z; h[3] = (_Float16)v.w;
            }
            *(half4v*)(Xs + r * PITCH + f4 * 4) = h;
        }
    }
    for (int i = t; i < FOUT * 16; i += 256) {
        int n = i >> 4, kg = i & 15;
        *(half8*)(Ws + n * PITCH + kg * 8) = *(const half8*)(Wt + n * 128 + kg * 8);
    }
    __syncthreads();

    int wave = t >> 6, lane = t & 63;
    int m = lane & 15, quad = lane >> 4;
    int wrow = wave * 16;
    constexpr int NCT = FOUT / 16;
    floatx4 acc[NCT];
#pragma unroll
    for (int c = 0; c < NCT; ++c) acc[c] = (floatx4){0.f, 0.f, 0.f, 0.f};

#pragma unroll
    for (int kc = 0; kc < 4; ++kc) {
        half8 a = *(const half8*)(Xs + (wrow + m) * PITCH + kc * 32 + quad * 8);
#pragma unroll
        for (int c = 0; c < NCT; ++c) {
            half8 b = *(const half8*)(Ws + (c * 16 + m) * PITCH + kc * 32 + quad * 8);
            acc[c] = __builtin_amdgcn_mfma_f32_16x16x32_f16(a, b, acc[c], 0, 0, 0);
        }
    }

    float dv[4];
    int rowb = row0 + wrow + quad * 4;
#pragma unroll
    for (int r = 0; r < 4; ++r) dv[r] = (rowb + r < NN) ? dinv[rowb + r] : 0.f;
#pragma unroll
    for (int c = 0; c < NCT; ++c) {
#pragma unroll
        for (int r = 0; r < 4; ++r) {
            int row = rowb + r;
            if (row < NN)
                Out[(size_t)row * FOUT + c * 16 + m] = __float2half(acc[c][r] * dv[r]);
        }
    }
}

// ---------- FUSED agg128 + mm2: G2 = fp16( dinv ⊙ (relu(dinv⊙csr_sum(G1)+b1) @ W2) ) ----------
// Block = 16 consecutive nodes (grid 6250 x 16 == NN exactly, no guards needed).
// Phase 1 (gather, unchanged structure): wave w, sub=lane>>4 -> node blk*16+w*4+sub,
// fl=lane&15 owns 8 features; relu'd row -> LDS (fp16, PITCH-padded).
// Phase 2 (MFMA): wave w computes cols [w*16,w*16+16) of all 16 rows vs Wt2.
__global__ __launch_bounds__(256) void k_agg_mm(
    const __half* __restrict__ G, const int* __restrict__ csr,
    const int* __restrict__ offs, const float* __restrict__ dinv,
    const float* __restrict__ bias1, const __half* __restrict__ Wt2,
    __half* __restrict__ G2) {
    constexpr int PITCH = 136;
    __shared__ _Float16 Brows[16 * PITCH];  // 16 relu'd B-rows
    __shared__ _Float16 Ws[64 * PITCH];     // Wt2 staged
    int t = threadIdx.x;
    // stage Wt2 (64 n-rows x 128 k, fp16 pre-transposed)
    for (int i = t; i < 64 * 16; i += 256) {
        int n = i >> 4, kg = i & 15;
        *(half8*)(Ws + n * PITCH + kg * 8) = *(const half8*)(Wt2 + n * 128 + kg * 8);
    }
    int wave = t >> 6, lane = t & 63;
    int sub = lane >> 4, fl = lane & 15;
    int ni = wave * 4 + sub;                 // 0..15 within block
    int node = blockIdx.x * 16 + ni;         // always < NN (6250*16 == NN)
    const _Float16* g = (const _Float16*)G;
    float acc[8];
    {
        half8 v = *(const half8*)(g + (size_t)node * 128 + fl * 8);  // self loop
#pragma unroll
        for (int j = 0; j < 8; ++j) acc[j] = (float)v[j];
    }
    int e0 = offs[node], e1 = offs[node + 1];
    int e = e0;
    for (; e + 4 <= e1; e += 4) {   // 4 independent 16 B gathers in flight
        int s0 = csr[e], s1 = csr[e + 1], s2 = csr[e + 2], s3 = csr[e + 3];
        half8 v0 = *(const half8*)(g + (size_t)s0 * 128 + fl * 8);
        half8 v1 = *(const half8*)(g + (size_t)s1 * 128 + fl * 8);
        half8 v2 = *(const half8*)(g + (size_t)s2 * 128 + fl * 8);
        half8 v3 = *(const half8*)(g + (size_t)s3 * 128 + fl * 8);
#pragma unroll
        for (int j = 0; j < 8; ++j)
            acc[j] += ((float)v0[j] + (float)v1[j]) + ((float)v2[j] + (float)v3[j]);
    }
    for (; e < e1; ++e) {
        half8 v = *(const half8*)(g + (size_t)csr[e] * 128 + fl * 8);
#pragma unroll
        for (int j = 0; j < 8; ++j) acc[j] += (float)v[j];
    }
    {
        float di = dinv[node];
        float4 b0 = *(const float4*)(bias1 + fl * 8);
        float4 b1 = *(const float4*)(bias1 + fl * 8 + 4);
        half8 h;
        h[0] = (_Float16)fmaxf(acc[0] * di + b0.x, 0.f);
        h[1] = (_Float16)fmaxf(acc[1] * di + b0.y, 0.f);
        h[2] = (_Float16)fmaxf(acc[2] * di + b0.z, 0.f);
        h[3] = (_Float16)fmaxf(acc[3] * di + b0.w, 0.f);
        h[4] = (_Float16)fmaxf(acc[4] * di + b1.x, 0.f);
        h[5] = (_Float16)fmaxf(acc[5] * di + b1.y, 0.f);
        h[6] = (_Float16)fmaxf(acc[6] * di + b1.z, 0.f);
        h[7] = (_Float16)fmaxf(acc[7] * di + b1.w, 0.f);
        *(half8*)(Brows + ni * PITCH + fl * 8) = h;
    }
    __syncthreads();
    // Phase 2: MFMA 16 rows x 16 cols per wave (verified f16 16x16x32 layouts)
    int m = lane & 15, quad = lane >> 4;
    floatx4 c = (floatx4){0.f, 0.f, 0.f, 0.f};
#pragma unroll
    for (int kc = 0; kc < 4; ++kc) {
        half8 a = *(const half8*)(Brows + m * PITCH + kc * 32 + quad * 8);
        half8 b = *(const half8*)(Ws + (wave * 16 + m) * PITCH + kc * 32 + quad * 8);
        c = __builtin_amdgcn_mfma_f32_16x16x32_f16(a, b, c, 0, 0, 0);
    }
    int rowb = blockIdx.x * 16 + quad * 4;
#pragma unroll
    for (int r = 0; r < 4; ++r) {
        float dv = dinv[rowb + r];
        G2[(size_t)(rowb + r) * 64 + wave * 16 + m] = __float2half(c[r] * dv);
    }
}

// ---------- aggregation: lane = 16 B (8 fp16 features); multiple nodes per wave ----------
template <int FOUT, bool RELU>
__global__ __launch_bounds__(256) void k_agg(
    const __half* __restrict__ G, const int* __restrict__ csr,
    const int* __restrict__ offs, const float* __restrict__ dinv,
    const float* __restrict__ bias, void* __restrict__ OutV) {
    constexpr int LPN = FOUT / 8;   // lanes per node
    constexpr int NPW = 64 / LPN;   // nodes per wave
    int t = threadIdx.x;
    int wave = t >> 6, lane = t & 63;
    int sub = lane / LPN, fl = lane % LPN;
    int node = (blockIdx.x * 4 + wave) * NPW + sub;
    if (node >= NN) return;
    const _Float16* g = (const _Float16*)G;
    float acc[8];
    {
        half8 v = *(const half8*)(g + (size_t)node * FOUT + fl * 8);  // self loop
#pragma unroll
        for (int j = 0; j < 8; ++j) acc[j] = (float)v[j];
    }
    int e0 = offs[node], e1 = offs[node + 1];
    int e = e0;
    for (; e + 4 <= e1; e += 4) {   // 4 independent 16 B gathers in flight
        int s0 = csr[e], s1 = csr[e + 1], s2 = csr[e + 2], s3 = csr[e + 3];
        half8 v0 = *(const half8*)(g + (size_t)s0 * FOUT + fl * 8);
        half8 v1 = *(const half8*)(g + (size_t)s1 * FOUT + fl * 8);
        half8 v2 = *(const half8*)(g + (size_t)s2 * FOUT + fl * 8);
        half8 v3 = *(const half8*)(g + (size_t)s3 * FOUT + fl * 8);
#pragma unroll
        for (int j = 0; j < 8; ++j)
            acc[j] += ((float)v0[j] + (float)v1[j]) + ((float)v2[j] + (float)v3[j]);
    }
    for (; e < e1; ++e) {
        half8 v = *(const half8*)(g + (size_t)csr[e] * FOUT + fl * 8);
#pragma unroll
        for (int j = 0; j < 8; ++j) acc[j] += (float)v[j];
    }
    float di = dinv[node];
    float4 b0 = *(const float4*)(bias + fl * 8);
    float4 b1 = *(const float4*)(bias + fl * 8 + 4);
    float o[8];
    o[0] = acc[0] * di + b0.x; o[1] = acc[1] * di + b0.y;
    o[2] = acc[2] * di + b0.z; o[3] = acc[3] * di + b0.w;
    o[4] = acc[4] * di + b1.x; o[5] = acc[5] * di + b1.y;
    o[6] = acc[6] * di + b1.z; o[7] = acc[7] * di + b1.w;
    if (RELU) {
        half8 h;
#pragma unroll
        for (int j = 0; j < 8; ++j) h[j] = (_Float16)fmaxf(o[j], 0.f);
        *(half8*)((__half*)OutV + (size_t)node * FOUT + fl * 8) = h;
    } else {
        float* Out = (float*)OutV + (size_t)node * FOUT + fl * 8;
        *(float4*)Out = make_float4(o[0], o[1], o[2], o[3]);
        *(float4*)(Out + 4) = make_float4(o[4], o[5], o[6], o[7]);
    }
}

// ---------- mean pool: 1 block/graph, 256 thr = 64 features x 4 row-slices ----------
__global__ __launch_bounds__(256) void k_pool(const float* __restrict__ H,
                                              const int* __restrict__ batch,
                                              float* __restrict__ out) {
    __shared__ float red[256];
    int gph = blockIdx.x;
    int lo = 0, hi = NN;
    while (lo < hi) { int m = (lo + hi) >> 1; if (batch[m] < gph) lo = m + 1; else hi = m; }
    int s0 = lo;
    hi = NN;
    while (lo < hi) { int m = (lo + hi) >> 1; if (batch[m] <= gph) lo = m + 1; else hi = m; }
    int s1 = lo;
    int t = threadIdx.x;
    int f = t & 63, rw = t >> 6;
    float s = 0.f;
    for (int n = s0 + rw; n < s1; n += 4) s += H[(size_t)n * 64 + f];
    red[t] = s;
    __syncthreads();
    if (rw == 0) {
        float tot = (red[f] + red[64 + f]) + (red[128 + f] + red[192 + f]);
        int cnt = s1 - s0;
        out[gph * 64 + f] = (cnt > 0) ? tot / (float)cnt : 0.f;
    }
}

extern "C" void kernel_launch(void* const* d_in, const int* in_sizes, int n_in,
                              void* d_out, int out_size, void* d_ws, size_t ws_size,
                              hipStream_t stream) {
    const float* x     = (const float*)d_in[0];
    const int*   ei    = (const int*)d_in[1];   // [2, NE] int32
    const int*   batch = (const int*)d_in[2];
    const float* W1    = (const float*)d_in[3];
    const float* b1    = (const float*)d_in[4];
    const float* W2    = (const float*)d_in[5];
    const float* b2    = (const float*)d_in[6];
    const int* esrc = ei;
    const int* edst = ei + NE;

    char* ws = (char*)d_ws;
    size_t off = 0;
    __half* G1  = (__half*)(ws + off); off += (size_t)NN * 128 * 2;  // fp16 row-major
    __half* G2  = (__half*)(ws + off); off += (size_t)NN * 64 * 2;   // fp16 row-major
    float* AGG2 = (float*)(ws + off);  off += (size_t)NN * 64 * 4;   // fp32 row-major
    int*   csr  = (int*)(ws + off);    off += (size_t)NE * 4;
    unsigned* pairbuf = (unsigned*)(ws + off); off += (size_t)NE * 4;
    int*   offs = (int*)(ws + off);    off += ((size_t)NN + 8) * 4;
    float* dinv = (float*)(ws + off);  off += (size_t)NN * 4;
    int*   bcnt = (int*)(ws + off);    off += 512 * 4;
    int*   bbase= (int*)(ws + off);    off += 512 * 4;
    int*   gcur = (int*)(ws + off);    off += 512 * 4;
    __half* Wt1 = (__half*)(ws + off); off += 128 * 128 * 2;
    __half* Wt2 = (__half*)(ws + off); off += 128 * 64 * 2;

    // CSR build: bucket hist -> scan -> sort -> fused offs/dinv/place (R15-identical)
    hipMemsetAsync(bcnt, 0, 512 * sizeof(int), stream);
    k_bhist<<<NCB, 256, 0, stream>>>(edst, bcnt);
    k_bscan<<<1, 512, 0, stream>>>(bcnt, bbase, gcur);
    k_csort<<<NCB, 256, 0, stream>>>(esrc, edst, gcur, pairbuf);
    k_offs_place<<<NBLK, 256, 0, stream>>>(pairbuf, bbase, offs, dinv, csr);

    // weight transpose+cast (tiny)
    k_wt<<<64, 256, 0, stream>>>(W1, Wt1, 128);
    k_wt<<<32, 256, 0, stream>>>(W2, Wt2, 64);

    const int MMB = (NN + 63) / 64;
    // layer 1 matmul: G1 = fp16(dinv ⊙ (x @ W1))
    k_mm_mfma<128, false><<<MMB, 256, 0, stream>>>(x, Wt1, dinv, G1);
    // FUSED layer-1 aggregation + layer-2 matmul: G2 = fp16(dinv ⊙ (relu(...) @ W2))
    k_agg_mm<<<NN / 16, 256, 0, stream>>>(G1, csr, offs, dinv, b1, Wt2, G2);
    // layer 2 aggregation: AGG2 = dinv ⊙ csr_sum(G2) + b2
    k_agg<64, false><<<(NN + 31) / 32, 256, 0, stream>>>(G2, csr, offs, dinv, b2, AGG2);

    k_pool<<<NG, 256, 0, stream>>>(AGG2, batch, (float*)d_out);
}